// Round 3
// baseline (256.472 us; speedup 1.0000x reference)
//
#include <hip/hip_runtime.h>
#include <hip/hip_cooperative_groups.h>
#include <math.h>

namespace cg = cooperative_groups;

// Problem constants (fixed by setup_inputs)
#define Nn 32
#define Cc 128
#define Ss 4096
#define Kk 64
#define NCHUNK 16
#define SCHUNK (Ss / NCHUNK)   // 256 pixels per block
#define ST 64                  // pixels per subtile
#define NSUB (SCHUNK / ST)     // 4 subtiles per block
#define BLK 256

// LDS strides (chosen for 16B-aligned fragment reads + even bank spread)
#define XCS 72    // xC [c][s] stride in ushorts (s-contig rows, 36 dw, 16B-aligned)
#define XTS 136   // xT [s][c] stride in ushorts (c-contig rows, 68 dw, 16B-aligned)
#define LKS 68    // Lbuf [s][k] stride in floats (aliases xT region: 68 dw == 136 u16)
#define AS  72    // aB [k][s] stride in ushorts
#define RS  17    // red stride in floats (odd -> conflict-free column reads)

typedef __attribute__((ext_vector_type(8))) short short8;   // bf16x8 MFMA frag
typedef __attribute__((ext_vector_type(4))) float float4v;  // fp32x4 MFMA acc

// 48.5 KiB shared block; all member offsets 16B-aligned by construction.
struct __align__(16) LdsA {
    unsigned short xC[Cc * XCS];   // 18432 B  raw-x bf16 [c][s]
    float Lbuf[ST * LKS];          // 17408 B  logits [s][k] / xT alias
    unsigned short aB[Kk * AS];    //  9216 B  a' bf16 [k][s]
    float red[ST * RS];            //  4352 B  ssq partials
    float invn[ST];                //   256 B
};

__device__ __forceinline__ unsigned f2bf(float f) {
    unsigned u = __builtin_bit_cast(unsigned, f);
    return (u + 0x7fffu + ((u >> 16) & 1u)) >> 16;   // RNE f32->bf16
}
__device__ __forceinline__ unsigned pack2(float a, float b) {
    return f2bf(a) | (f2bf(b) << 16);
}

// Phase A: stage bf16 x (2 layouts) -> L2-norm -> MFMA logits -> softmax ->
// MFMA VLAD (persistent acc) -> PLAIN STORES to per-chunk vladp/asump.
// MFMA 16x16x32 bf16 layouts (HW-verified per guide):
//   A[m=lane&15][k=quad*8+j], B[k=quad*8+j][n=lane&15], D col=lane&15 row=4*quad+reg.
__device__ __forceinline__ void run_phaseA(
    LdsA& S,
    const float* __restrict__ x,
    const float* __restrict__ conv_w,
    const float* __restrict__ conv_b,
    float* __restrict__ vladp,   // [NCHUNK][Nn][Kk][Cc]
    float* __restrict__ asump,   // [NCHUNK][Nn][Kk]
    int chunk, int n)
{
    unsigned short* xT = (unsigned short*)S.Lbuf;   // raw-x bf16 [s][c]

    const int t    = threadIdx.x;
    const int w    = t >> 6;      // wave id: k-rows 16w..16w+15
    const int l    = t & 63;
    const int m    = l & 15;
    const int quad = l >> 4;
    const int p    = t >> 2;      // softmax pixel
    const int ii   = t & 3;       // softmax k-slice

    // ---- one-time: conv_w A-fragments (bf16, regs) + bias for D rows ----
    short8 wfrag[4];
    {
        const float* wr_ = conv_w + (16 * w + m) * Cc;
#pragma unroll
        for (int ks = 0; ks < 4; ++ks) {
            float4 wa = *(const float4*)(wr_ + 32 * ks + 8 * quad);
            float4 wb = *(const float4*)(wr_ + 32 * ks + 8 * quad + 4);
            union { short8 s8; unsigned u[4]; } W_;
            W_.u[0] = pack2(wa.x, wa.y);
            W_.u[1] = pack2(wa.z, wa.w);
            W_.u[2] = pack2(wb.x, wb.y);
            W_.u[3] = pack2(wb.z, wb.w);
            wfrag[ks] = W_.s8;
        }
    }
    float bias_r[4];
#pragma unroll
    for (int r = 0; r < 4; ++r) bias_r[r] = conv_b[16 * w + 4 * quad + r];

    float4v acc[8];               // VLAD acc: 16k x 128c per wave, persistent
#pragma unroll
    for (int nt = 0; nt < 8; ++nt) acc[nt] = (float4v){0.f, 0.f, 0.f, 0.f};
    float asum_part[16];
#pragma unroll
    for (int j = 0; j < 16; ++j) asum_part[j] = 0.f;

    const float* xn = x + (size_t)n * Cc * Ss;

    for (int sub = 0; sub < NSUB; ++sub) {
        const int s0 = chunk * SCHUNK + sub * ST;
        __syncthreads();  // prior GEMM2 reads of xC/aB done

        // ---- stage: fp32 load -> ssq partials + bf16 xC [c][s] ----
        {
            float sp0 = 0.f, sp1 = 0.f, sp2 = 0.f, sp3 = 0.f;
            const int sq = (t & 15) << 2;
#pragma unroll
            for (int r = 0; r < 8; ++r) {
                int c = (t >> 4) + 16 * r;
                float4 v = *(const float4*)(xn + (size_t)c * Ss + s0 + sq);
                sp0 += v.x * v.x; sp1 += v.y * v.y;
                sp2 += v.z * v.z; sp3 += v.w * v.w;
                uint2 pk = make_uint2(pack2(v.x, v.y), pack2(v.z, v.w));
                *(uint2*)&S.xC[c * XCS + sq] = pk;
            }
            S.red[(sq + 0) * RS + (t >> 4)] = sp0;
            S.red[(sq + 1) * RS + (t >> 4)] = sp1;
            S.red[(sq + 2) * RS + (t >> 4)] = sp2;
            S.red[(sq + 3) * RS + (t >> 4)] = sp3;
        }
        __syncthreads();

        // ---- invn (t<64) ----
        if (t < ST) {
            float tot = 0.f;
#pragma unroll
            for (int i = 0; i < 16; ++i) tot += S.red[t * RS + i];
            S.invn[t] = 1.0f / fmaxf(sqrtf(tot), 1e-12f);
        }
        // ---- build xT [s][c] from xC (16B writes; lane-spread over s) ----
        {
            int s = t & 63, oct0 = t >> 6;
#pragma unroll
            for (int q = 0; q < 4; ++q) {
                int oct = oct0 + 4 * q;   // c-octet 0..15
                uint4 dd;
                dd.x = (unsigned)S.xC[(8 * oct + 0) * XCS + s] | ((unsigned)S.xC[(8 * oct + 1) * XCS + s] << 16);
                dd.y = (unsigned)S.xC[(8 * oct + 2) * XCS + s] | ((unsigned)S.xC[(8 * oct + 3) * XCS + s] << 16);
                dd.z = (unsigned)S.xC[(8 * oct + 4) * XCS + s] | ((unsigned)S.xC[(8 * oct + 5) * XCS + s] << 16);
                dd.w = (unsigned)S.xC[(8 * oct + 6) * XCS + s] | ((unsigned)S.xC[(8 * oct + 7) * XCS + s] << 16);
                *(uint4*)&xT[s * XTS + 8 * oct] = dd;
            }
        }
        __syncthreads();

        // ---- GEMM1 (MFMA): L[16w+k][s] = W x rawX, wave does 4 s-tiles x 4 c-steps
        float4v Lr[4];
#pragma unroll
        for (int nt = 0; nt < 4; ++nt) Lr[nt] = (float4v){0.f, 0.f, 0.f, 0.f};
#pragma unroll
        for (int nt = 0; nt < 4; ++nt) {
#pragma unroll
            for (int ks = 0; ks < 4; ++ks) {
                short8 b = *(const short8*)&xT[(16 * nt + m) * XTS + 32 * ks + 8 * quad];
                Lr[nt] = __builtin_amdgcn_mfma_f32_16x16x32_bf16(wfrag[ks], b, Lr[nt], 0, 0, 0);
            }
        }
        __syncthreads();  // all xT reads done -> safe to overwrite with Lbuf

        // epilogue: *invn[s] + bias[k]; write [s][k] fp32
#pragma unroll
        for (int nt = 0; nt < 4; ++nt) {
            float iv = S.invn[16 * nt + m];
            float4 o;
            o.x = Lr[nt].x * iv + bias_r[0];
            o.y = Lr[nt].y * iv + bias_r[1];
            o.z = Lr[nt].z * iv + bias_r[2];
            o.w = Lr[nt].w * iv + bias_r[3];
            *(float4*)&S.Lbuf[(16 * nt + m) * LKS + 16 * w + 4 * quad] = o;
        }
        __syncthreads();

        // ---- softmax over k per pixel p (4-thread team via shfl) ----
        {
            float lv[16];
#pragma unroll
            for (int j = 0; j < 16; ++j) lv[j] = S.Lbuf[p * LKS + ii + 4 * j];
            float mx = lv[0];
#pragma unroll
            for (int j = 1; j < 16; ++j) mx = fmaxf(mx, lv[j]);
            mx = fmaxf(mx, __shfl_xor(mx, 1));
            mx = fmaxf(mx, __shfl_xor(mx, 2));
            float e[16];
            float lsum = 0.f;
#pragma unroll
            for (int j = 0; j < 16; ++j) { e[j] = __expf(lv[j] - mx); lsum += e[j]; }
            lsum += __shfl_xor(lsum, 1);
            lsum += __shfl_xor(lsum, 2);
            float itot = 1.0f / lsum;
            float sca  = itot * S.invn[p];   // fold invn into a' (x in GEMM2 is raw)
#pragma unroll
            for (int j = 0; j < 16; ++j) {
                float av = e[j] * itot;
                asum_part[j] += av;                               // raw a for centroid term
                S.aB[(ii + 4 * j) * AS + p] = (unsigned short)f2bf(e[j] * sca);
            }
        }
        __syncthreads();

        // ---- GEMM2 (MFMA): V[16w+k][c] += a'[k][s] x rawX^T[s][c] ----
#pragma unroll
        for (int ks = 0; ks < 2; ++ks) {
            short8 af = *(const short8*)&S.aB[(16 * w + m) * AS + 32 * ks + 8 * quad];
#pragma unroll
            for (int nt = 0; nt < 8; ++nt) {
                short8 bf_ = *(const short8*)&S.xC[(16 * nt + m) * XCS + 32 * ks + 8 * quad];
                acc[nt] = __builtin_amdgcn_mfma_f32_16x16x32_bf16(af, bf_, acc[nt], 0, 0, 0);
            }
        }
    }

    // ---- commit vlad partials as PLAIN STORES: lane holds D[k=16w+4quad+r][c=16nt+m]
    {
        float* vb = vladp + ((((size_t)chunk * Nn + n) * Kk) + 16 * w + 4 * quad) * Cc + m;
#pragma unroll
        for (int nt = 0; nt < 8; ++nt) {
            vb[0 * Cc + 16 * nt] = acc[nt].x;
            vb[1 * Cc + 16 * nt] = acc[nt].y;
            vb[2 * Cc + 16 * nt] = acc[nt].z;
            vb[3 * Cc + 16 * nt] = acc[nt].w;
        }
    }

    // ---- block-reduce asum then plain store per k (reuse Lbuf) ----
    __syncthreads();
#pragma unroll
    for (int j = 0; j < 16; ++j) S.Lbuf[p * LKS + ii + 4 * j] = asum_part[j];
    __syncthreads();
    if (t < Kk) {
        float s_ = 0.f;
        for (int p2 = 0; p2 < ST; ++p2) s_ += S.Lbuf[p2 * LKS + t];
        asump[((size_t)chunk * Nn + n) * Kk + t] = s_;
    }
}

// Phase B: block bid in [0, Nn*8): (n2, kgroup of 8 k's). Chunk-reduce vladp ->
// intra-norm scale -> lastfc partial -> 4 atomicAdds/thread into zeroed out.
__device__ __forceinline__ void run_phaseB(
    LdsA& S,
    const float* __restrict__ vladp,
    const float* __restrict__ asump,
    const float* __restrict__ centroids,
    const float* __restrict__ fc_w,
    float* __restrict__ out,
    int bid)
{
    const int t  = threadIdx.x;
    const int n2 = bid >> 3;
    const int kg = bid & 7;
    const int kl = t >> 5;        // k within group 0..7
    const int c4 = t & 31;        // float4 column index
    const int k2 = 8 * kg + kl;

    float* asum_s  = (float*)S.aB;        // 8 floats (alias)
    float* scale_s = asum_s + 8;          // 8 floats
    float4* osum   = (float4*)S.xC;       // [8][32] float4 = 4 KB

    // chunk-reduce vladp -> v (each thread owns 4 c's of one k)
    float4 v = make_float4(0.f, 0.f, 0.f, 0.f);
    const float* vp = vladp + ((size_t)n2 * Kk + k2) * Cc + 4 * c4;
#pragma unroll
    for (int ch = 0; ch < NCHUNK; ++ch) {
        float4 u = *(const float4*)(vp + (size_t)ch * Nn * Kk * Cc);
        v.x += u.x; v.y += u.y; v.z += u.z; v.w += u.w;
    }
    // chunk-reduce asum (8 threads)
    if (t < 8) {
        float a = 0.f;
#pragma unroll
        for (int ch = 0; ch < NCHUNK; ++ch)
            a += asump[((size_t)ch * Nn + n2) * Kk + 8 * kg + t];
        asum_s[t] = a;
    }
    __syncthreads();

    const float a2 = asum_s[kl];
    float4 cv = *(const float4*)(centroids + (size_t)k2 * Cc + 4 * c4);
    float dx = v.x - a2 * cv.x;
    float dy = v.y - a2 * cv.y;
    float dz = v.z - a2 * cv.z;
    float dw = v.w - a2 * cv.w;

    float ssq = dx * dx + dy * dy + dz * dz + dw * dw;
    ssq += __shfl_xor(ssq, 1);
    ssq += __shfl_xor(ssq, 2);
    ssq += __shfl_xor(ssq, 4);
    ssq += __shfl_xor(ssq, 8);
    ssq += __shfl_xor(ssq, 16);
    if ((t & 31) == 0)
        scale_s[kl] = fc_w[k2] / fmaxf(sqrtf(ssq), 1e-12f);
    __syncthreads();

    const float sc = scale_s[kl];
    osum[kl * 32 + c4] = make_float4(sc * dx, sc * dy, sc * dz, sc * dw);
    __syncthreads();

    if (t < 32) {
        float4 tot = osum[t];
#pragma unroll
        for (int kl2 = 1; kl2 < 8; ++kl2) {
            float4 o2 = osum[kl2 * 32 + t];
            tot.x += o2.x; tot.y += o2.y; tot.z += o2.z; tot.w += o2.w;
        }
        atomicAdd(&out[n2 * Cc + 4 * t + 0], tot.x);
        atomicAdd(&out[n2 * Cc + 4 * t + 1], tot.y);
        atomicAdd(&out[n2 * Cc + 4 * t + 2], tot.z);
        atomicAdd(&out[n2 * Cc + 4 * t + 3], tot.w);
    }
}

// ---- fused cooperative path (1 dispatch, no memset, no commit atomics) ----
__global__ __launch_bounds__(BLK, 3) void netvlad_fused(
    const float* __restrict__ x,
    const float* __restrict__ conv_w,
    const float* __restrict__ conv_b,
    const float* __restrict__ centroids,
    const float* __restrict__ fc_w,
    float* __restrict__ out,
    float* __restrict__ vladp,
    float* __restrict__ asump)
{
    __shared__ LdsA S;
    const int bid = blockIdx.y * NCHUNK + blockIdx.x;

    // out is poisoned each call: block 0 zeroes it (4096 floats) pre-sync
    if (bid == 0) {
        float4 z4 = make_float4(0.f, 0.f, 0.f, 0.f);
#pragma unroll
        for (int i = 0; i < 4; ++i)
            ((float4*)out)[threadIdx.x + 256 * i] = z4;
    }

    run_phaseA(S, x, conv_w, conv_b, vladp, asump, blockIdx.x, blockIdx.y);

    __threadfence();
    cg::this_grid().sync();

    if (bid < Nn * 8)
        run_phaseB(S, vladp, asump, centroids, fc_w, out, bid);
}

// ---- fallback path: same bodies as two ordinary kernels ----
__global__ __launch_bounds__(BLK, 3) void netvlad_pA(
    const float* __restrict__ x,
    const float* __restrict__ conv_w,
    const float* __restrict__ conv_b,
    float* __restrict__ vladp,
    float* __restrict__ asump)
{
    __shared__ LdsA S;
    run_phaseA(S, x, conv_w, conv_b, vladp, asump, blockIdx.x, blockIdx.y);
}

__global__ __launch_bounds__(BLK) void netvlad_pB(
    const float* __restrict__ vladp,
    const float* __restrict__ asump,
    const float* __restrict__ centroids,
    const float* __restrict__ fc_w,
    float* __restrict__ out)
{
    __shared__ LdsA S;
    run_phaseB(S, vladp, asump, centroids, fc_w, out, blockIdx.x);
}

extern "C" void kernel_launch(void* const* d_in, const int* in_sizes, int n_in,
                              void* d_out, int out_size, void* d_ws, size_t ws_size,
                              hipStream_t stream) {
    (void)in_sizes; (void)n_in; (void)out_size; (void)ws_size;
    const float* x         = (const float*)d_in[0];
    const float* conv_w    = (const float*)d_in[1];
    const float* conv_b    = (const float*)d_in[2];
    const float* centroids = (const float*)d_in[3];
    const float* fc_w      = (const float*)d_in[4];
    float* out = (float*)d_out;

    float* vladp = (float*)d_ws;                                   // [16][32][64][128] = 16 MB
    float* asump = vladp + (size_t)NCHUNK * Nn * Kk * Cc;          // [16][32][64] = 128 KB

    dim3 grid(NCHUNK, Nn);
    dim3 block(BLK);
    void* args[] = {(void*)&x, (void*)&conv_w, (void*)&conv_b, (void*)&centroids,
                    (void*)&fc_w, (void*)&out, (void*)&vladp, (void*)&asump};
    hipError_t rc = hipLaunchCooperativeKernel((void*)netvlad_fused, grid, block,
                                               args, 0, stream);
    if (rc != hipSuccess) {
        // Non-cooperative fallback: zero out for phase-B atomics, then 2 kernels.
        hipMemsetAsync(out, 0, (size_t)Nn * Cc * sizeof(float), stream);
        netvlad_pA<<<grid, block, 0, stream>>>(x, conv_w, conv_b, vladp, asump);
        netvlad_pB<<<dim3(Nn * 8), block, 0, stream>>>(vladp, asump, centroids, fc_w, out);
    }
}

// Round 4
// 116.052 us; speedup vs baseline: 2.2100x; 2.2100x over previous
//
#include <hip/hip_runtime.h>
#include <math.h>

// Problem constants (fixed by setup_inputs)
#define Nn 32
#define Cc 128
#define Ss 4096
#define Kk 64
#define NCHUNK 16
#define SCHUNK (Ss / NCHUNK)   // 256 pixels per block
#define ST 64                  // pixels per subtile
#define NSUB (SCHUNK / ST)     // 4 subtiles per block
#define BLK 256

// LDS strides (chosen for 16B-aligned fragment reads + even bank spread)
#define XCS 72    // xC [c][s] stride in ushorts (s-contig rows, 36 dw, 16B-aligned)
#define XTS 136   // xT [s][c] stride in ushorts (c-contig rows, 68 dw, 16B-aligned)
#define LKS 68    // Lbuf [s][k] stride in floats (aliases xT region: 68 dw == 136 u16)
#define AS  72    // aB [k][s] stride in ushorts
#define RS  17    // red stride in floats (odd -> conflict-free column reads)

typedef __attribute__((ext_vector_type(8))) short short8;   // bf16x8 MFMA frag
typedef __attribute__((ext_vector_type(4))) float float4v;  // fp32x4 MFMA acc

__device__ __forceinline__ unsigned f2bf(float f) {
    unsigned u = __builtin_bit_cast(unsigned, f);
    return (u + 0x7fffu + ((u >> 16) & 1u)) >> 16;   // RNE f32->bf16
}
__device__ __forceinline__ unsigned pack2(float a, float b) {
    return f2bf(a) | (f2bf(b) << 16);
}

// Fused main: stage bf16 x (2 layouts) -> L2-norm -> MFMA logits -> softmax ->
// MFMA VLAD (persistent acc) -> PLAIN STORES to per-chunk vladp/asump.
// (256,2): round-3 showed (256,3)'s 170-VGPR cap spills softmax temps -> 2x slow.
// MFMA 16x16x32 bf16 layouts (HW-verified per guide):
//   A[m=lane&15][k=quad*8+j], B[k=quad*8+j][n=lane&15], D col=lane&15 row=4*quad+reg.
__global__ __launch_bounds__(BLK, 2) void netvlad_main(
    const float* __restrict__ x,
    const float* __restrict__ conv_w,
    const float* __restrict__ conv_b,
    float* __restrict__ vladp,   // [NCHUNK][Nn][Kk][Cc]  16 MB
    float* __restrict__ asump)   // [NCHUNK][Nn][Kk]      128 KB
{
    __shared__ __align__(16) unsigned short xC[Cc * XCS];  // 18432 B raw-x bf16 [c][s]
    __shared__ __align__(16) float Lbuf[ST * LKS];         // 17408 B logits [s][k] / xT alias
    __shared__ __align__(16) unsigned short aB[Kk * AS];   // 9216 B  a' bf16 [k][s]
    __shared__ float red[ST * RS];                         // 4352 B  ssq partials
    __shared__ float invn[ST];
    unsigned short* xT = (unsigned short*)Lbuf;            // raw-x bf16 [s][c]

    const int t     = threadIdx.x;
    const int n     = blockIdx.y;
    const int chunk = blockIdx.x;
    const int w    = t >> 6;      // wave id: k-rows 16w..16w+15
    const int l    = t & 63;
    const int m    = l & 15;
    const int quad = l >> 4;
    const int p    = t >> 2;      // softmax pixel
    const int ii   = t & 3;       // softmax k-slice

    // ---- one-time: conv_w A-fragments (bf16, regs) + bias for D rows ----
    short8 wfrag[4];
    {
        const float* wr_ = conv_w + (16 * w + m) * Cc;
#pragma unroll
        for (int ks = 0; ks < 4; ++ks) {
            float4 wa = *(const float4*)(wr_ + 32 * ks + 8 * quad);
            float4 wb = *(const float4*)(wr_ + 32 * ks + 8 * quad + 4);
            union { short8 s8; unsigned u[4]; } W_;
            W_.u[0] = pack2(wa.x, wa.y);
            W_.u[1] = pack2(wa.z, wa.w);
            W_.u[2] = pack2(wb.x, wb.y);
            W_.u[3] = pack2(wb.z, wb.w);
            wfrag[ks] = W_.s8;
        }
    }
    float bias_r[4];
#pragma unroll
    for (int r = 0; r < 4; ++r) bias_r[r] = conv_b[16 * w + 4 * quad + r];

    float4v acc[8];               // VLAD acc: 16k x 128c per wave, persistent
#pragma unroll
    for (int nt = 0; nt < 8; ++nt) acc[nt] = (float4v){0.f, 0.f, 0.f, 0.f};
    float asum_part[16];
#pragma unroll
    for (int j = 0; j < 16; ++j) asum_part[j] = 0.f;

    const float* xn = x + (size_t)n * Cc * Ss;

    // ---- register prefetch of subtile 0 ----
    const int sq   = (t & 15) << 2;
    const int crow = t >> 4;
    const float* xbase = xn + (size_t)crow * Ss + chunk * SCHUNK + sq;
    float4 pf[8];
#pragma unroll
    for (int r = 0; r < 8; ++r)
        pf[r] = *(const float4*)(xbase + (size_t)(16 * r) * Ss);

    for (int sub = 0; sub < NSUB; ++sub) {
        __syncthreads();  // prior GEMM2 reads of xC/aB done

        // ---- stage: consume prefetched fp32 -> ssq partials + bf16 xC [c][s] ----
        {
            float sp0 = 0.f, sp1 = 0.f, sp2 = 0.f, sp3 = 0.f;
#pragma unroll
            for (int r = 0; r < 8; ++r) {
                float4 v = pf[r];
                sp0 += v.x * v.x; sp1 += v.y * v.y;
                sp2 += v.z * v.z; sp3 += v.w * v.w;
                uint2 pk = make_uint2(pack2(v.x, v.y), pack2(v.z, v.w));
                *(uint2*)&xC[(crow + 16 * r) * XCS + sq] = pk;
            }
            red[(sq + 0) * RS + crow] = sp0;
            red[(sq + 1) * RS + crow] = sp1;
            red[(sq + 2) * RS + crow] = sp2;
            red[(sq + 3) * RS + crow] = sp3;
        }
        // ---- issue next subtile's loads (fly under GEMM1/softmax/GEMM2) ----
        if (sub < NSUB - 1) {
#pragma unroll
            for (int r = 0; r < 8; ++r)
                pf[r] = *(const float4*)(xbase + (size_t)(16 * r) * Ss + (sub + 1) * ST);
        }
        __syncthreads();

        // ---- invn (t<64) ----
        if (t < ST) {
            float tot = 0.f;
#pragma unroll
            for (int i = 0; i < 16; ++i) tot += red[t * RS + i];
            invn[t] = 1.0f / fmaxf(sqrtf(tot), 1e-12f);
        }
        // ---- build xT [s][c] from xC (16B writes; lane-spread over s) ----
        {
            int s = t & 63, oct0 = t >> 6;
#pragma unroll
            for (int q = 0; q < 4; ++q) {
                int oct = oct0 + 4 * q;   // c-octet 0..15
                uint4 dd;
                dd.x = (unsigned)xC[(8 * oct + 0) * XCS + s] | ((unsigned)xC[(8 * oct + 1) * XCS + s] << 16);
                dd.y = (unsigned)xC[(8 * oct + 2) * XCS + s] | ((unsigned)xC[(8 * oct + 3) * XCS + s] << 16);
                dd.z = (unsigned)xC[(8 * oct + 4) * XCS + s] | ((unsigned)xC[(8 * oct + 5) * XCS + s] << 16);
                dd.w = (unsigned)xC[(8 * oct + 6) * XCS + s] | ((unsigned)xC[(8 * oct + 7) * XCS + s] << 16);
                *(uint4*)&xT[s * XTS + 8 * oct] = dd;
            }
        }
        __syncthreads();

        // ---- GEMM1 (MFMA): L[16w+k][s] = W x rawX, wave does 4 s-tiles x 4 c-steps
        float4v Lr[4];
#pragma unroll
        for (int nt = 0; nt < 4; ++nt) Lr[nt] = (float4v){0.f, 0.f, 0.f, 0.f};
#pragma unroll
        for (int nt = 0; nt < 4; ++nt) {
#pragma unroll
            for (int ks = 0; ks < 4; ++ks) {
                short8 b = *(const short8*)&xT[(16 * nt + m) * XTS + 32 * ks + 8 * quad];
                Lr[nt] = __builtin_amdgcn_mfma_f32_16x16x32_bf16(wfrag[ks], b, Lr[nt], 0, 0, 0);
            }
        }
        __syncthreads();  // all xT reads done -> safe to overwrite with Lbuf

        // epilogue: *invn[s] + bias[k]; write [s][k] fp32
#pragma unroll
        for (int nt = 0; nt < 4; ++nt) {
            float iv = invn[16 * nt + m];
            float4 o;
            o.x = Lr[nt].x * iv + bias_r[0];
            o.y = Lr[nt].y * iv + bias_r[1];
            o.z = Lr[nt].z * iv + bias_r[2];
            o.w = Lr[nt].w * iv + bias_r[3];
            *(float4*)&Lbuf[(16 * nt + m) * LKS + 16 * w + 4 * quad] = o;
        }
        __syncthreads();

        // ---- softmax over k per pixel p (4-thread team via shfl) ----
        {
            float lv[16];
#pragma unroll
            for (int j = 0; j < 16; ++j) lv[j] = Lbuf[p * LKS + ii + 4 * j];
            float mx = lv[0];
#pragma unroll
            for (int j = 1; j < 16; ++j) mx = fmaxf(mx, lv[j]);
            mx = fmaxf(mx, __shfl_xor(mx, 1));
            mx = fmaxf(mx, __shfl_xor(mx, 2));
            float e[16];
            float lsum = 0.f;
#pragma unroll
            for (int j = 0; j < 16; ++j) { e[j] = __expf(lv[j] - mx); lsum += e[j]; }
            lsum += __shfl_xor(lsum, 1);
            lsum += __shfl_xor(lsum, 2);
            float itot = 1.0f / lsum;
            float sca  = itot * invn[p];   // fold invn into a' (x in GEMM2 is raw)
#pragma unroll
            for (int j = 0; j < 16; ++j) {
                float av = e[j] * itot;
                asum_part[j] += av;                               // raw a for centroid term
                aB[(ii + 4 * j) * AS + p] = (unsigned short)f2bf(e[j] * sca);
            }
        }
        __syncthreads();

        // ---- GEMM2 (MFMA): V[16w+k][c] += a'[k][s] x rawX^T[s][c] ----
#pragma unroll
        for (int ks = 0; ks < 2; ++ks) {
            short8 af = *(const short8*)&aB[(16 * w + m) * AS + 32 * ks + 8 * quad];
#pragma unroll
            for (int nt = 0; nt < 8; ++nt) {
                short8 bf_ = *(const short8*)&xC[(16 * nt + m) * XCS + 32 * ks + 8 * quad];
                acc[nt] = __builtin_amdgcn_mfma_f32_16x16x32_bf16(af, bf_, acc[nt], 0, 0, 0);
            }
        }
    }

    // ---- commit vlad partials as PLAIN STORES (no atomics, no ws memset):
    //      lane holds D[k=16w+4quad+r][c=16nt+m]
    {
        float* vb = vladp + ((((size_t)chunk * Nn + n) * Kk) + 16 * w + 4 * quad) * Cc + m;
#pragma unroll
        for (int nt = 0; nt < 8; ++nt) {
            vb[0 * Cc + 16 * nt] = acc[nt].x;
            vb[1 * Cc + 16 * nt] = acc[nt].y;
            vb[2 * Cc + 16 * nt] = acc[nt].z;
            vb[3 * Cc + 16 * nt] = acc[nt].w;
        }
    }

    // ---- block-reduce asum then plain store per k (reuse Lbuf) ----
    __syncthreads();
#pragma unroll
    for (int j = 0; j < 16; ++j) Lbuf[p * LKS + ii + 4 * j] = asum_part[j];
    __syncthreads();
    if (t < Kk) {
        float s_ = 0.f;
        for (int p2 = 0; p2 < ST; ++p2) s_ += Lbuf[p2 * LKS + t];
        asump[((size_t)chunk * Nn + n) * Kk + t] = s_;
    }
}

// Finalize, 256 blocks = (n2, kgroup of 8 k's): chunk-reduce vladp -> intra-norm
// scale -> lastfc partial -> 4 atomicAdds/thread into zeroed out.
// (8x the parallelism of the old 32-block finalize.)
__global__ __launch_bounds__(BLK) void netvlad_final(
    const float* __restrict__ vladp,
    const float* __restrict__ asump,
    const float* __restrict__ centroids,
    const float* __restrict__ fc_w,
    float* __restrict__ out)
{
    __shared__ float asum_s[8];
    __shared__ float scale_s[8];
    __shared__ float4 osum[8 * 32];

    const int t   = threadIdx.x;
    const int bid = blockIdx.x;
    const int n2  = bid >> 3;
    const int kg  = bid & 7;
    const int kl  = t >> 5;       // k within group 0..7
    const int c4  = t & 31;       // float4 column index
    const int k2  = 8 * kg + kl;

    // chunk-reduce vladp -> v (each thread owns 4 c's of one k)
    float4 v = make_float4(0.f, 0.f, 0.f, 0.f);
    const float* vp = vladp + ((size_t)n2 * Kk + k2) * Cc + 4 * c4;
#pragma unroll
    for (int ch = 0; ch < NCHUNK; ++ch) {
        float4 u = *(const float4*)(vp + (size_t)ch * Nn * Kk * Cc);
        v.x += u.x; v.y += u.y; v.z += u.z; v.w += u.w;
    }
    // chunk-reduce asum (8 threads)
    if (t < 8) {
        float a = 0.f;
#pragma unroll
        for (int ch = 0; ch < NCHUNK; ++ch)
            a += asump[((size_t)ch * Nn + n2) * Kk + 8 * kg + t];
        asum_s[t] = a;
    }
    __syncthreads();

    const float a2 = asum_s[kl];
    float4 cv = *(const float4*)(centroids + (size_t)k2 * Cc + 4 * c4);
    float dx = v.x - a2 * cv.x;
    float dy = v.y - a2 * cv.y;
    float dz = v.z - a2 * cv.z;
    float dw = v.w - a2 * cv.w;

    float ssq = dx * dx + dy * dy + dz * dz + dw * dw;
    ssq += __shfl_xor(ssq, 1);
    ssq += __shfl_xor(ssq, 2);
    ssq += __shfl_xor(ssq, 4);
    ssq += __shfl_xor(ssq, 8);
    ssq += __shfl_xor(ssq, 16);
    if ((t & 31) == 0)
        scale_s[kl] = fc_w[k2] / fmaxf(sqrtf(ssq), 1e-12f);
    __syncthreads();

    const float sc = scale_s[kl];
    osum[kl * 32 + c4] = make_float4(sc * dx, sc * dy, sc * dz, sc * dw);
    __syncthreads();

    if (t < 32) {
        float4 tot = osum[t];
#pragma unroll
        for (int kl2 = 1; kl2 < 8; ++kl2) {
            float4 o2 = osum[kl2 * 32 + t];
            tot.x += o2.x; tot.y += o2.y; tot.z += o2.z; tot.w += o2.w;
        }
        atomicAdd(&out[n2 * Cc + 4 * t + 0], tot.x);
        atomicAdd(&out[n2 * Cc + 4 * t + 1], tot.y);
        atomicAdd(&out[n2 * Cc + 4 * t + 2], tot.z);
        atomicAdd(&out[n2 * Cc + 4 * t + 3], tot.w);
    }
}

extern "C" void kernel_launch(void* const* d_in, const int* in_sizes, int n_in,
                              void* d_out, int out_size, void* d_ws, size_t ws_size,
                              hipStream_t stream) {
    (void)in_sizes; (void)n_in; (void)out_size; (void)ws_size;
    const float* x         = (const float*)d_in[0];
    const float* conv_w    = (const float*)d_in[1];
    const float* conv_b    = (const float*)d_in[2];
    const float* centroids = (const float*)d_in[3];
    const float* fc_w      = (const float*)d_in[4];
    float* out = (float*)d_out;

    float* vladp = (float*)d_ws;                                   // [16][32][64][128] = 16 MB
    float* asump = vladp + (size_t)NCHUNK * Nn * Kk * Cc;          // [16][32][64] = 128 KB

    // only out needs zeroing (16 KB) for finalize's accumulation atomics
    hipMemsetAsync(out, 0, (size_t)Nn * Cc * sizeof(float), stream);

    dim3 grid(NCHUNK, Nn);
    netvlad_main<<<grid, BLK, 0, stream>>>(x, conv_w, conv_b, vladp, asump);
    netvlad_final<<<dim3(Nn * 8), BLK, 0, stream>>>(vladp, asump, centroids, fc_w, out);
}

// Round 5
// 113.787 us; speedup vs baseline: 2.2540x; 1.0199x over previous
//
#include <hip/hip_runtime.h>
#include <math.h>

// Problem constants (fixed by setup_inputs)
#define Nn 32
#define Cc 128
#define Ss 4096
#define Kk 64
#define NCHUNK 16
#define SCHUNK (Ss / NCHUNK)   // 256 pixels per block
#define ST 64                  // pixels per subtile
#define NSUB (SCHUNK / ST)     // 4 subtiles per block
#define BLK 256

// LDS strides (chosen for 16B-aligned fragment reads + even bank spread)
#define XCS 72    // xC [c][s] stride in ushorts (s-contig rows, 36 dw, 16B-aligned)
#define XTS 136   // xT [s][c] stride in ushorts (c-contig rows, 68 dw, 16B-aligned)
#define LKS 68    // Lbuf [s][k] stride in floats (aliases xT region: 68 dw == 136 u16)
#define AS  72    // aB [k][s] stride in ushorts
#define RS  17    // red stride in floats (odd -> conflict-free column reads)

typedef __attribute__((ext_vector_type(8))) short short8;   // bf16x8 MFMA frag
typedef __attribute__((ext_vector_type(4))) float float4v;  // fp32x4 MFMA acc

__device__ __forceinline__ unsigned f2bf(float f) {
    unsigned u = __builtin_bit_cast(unsigned, f);
    return (u + 0x7fffu + ((u >> 16) & 1u)) >> 16;   // RNE f32->bf16
}
__device__ __forceinline__ unsigned pack2(float a, float b) {
    return f2bf(a) | (f2bf(b) << 16);
}

// LDS-only barrier: waits LDS ops (cross-wave handoff) but does NOT drain
// vmcnt — in-flight global prefetch loads survive the barrier (T4 pattern).
// All cross-thread communication in this kernel is through LDS; global reads
// are same-thread (compiler inserts its own vmcnt waits before register use).
__device__ __forceinline__ void bar_lds() {
    asm volatile("s_waitcnt lgkmcnt(0)" ::: "memory");
    __builtin_amdgcn_s_barrier();
    asm volatile("" ::: "memory");
}

// Fused main: stage bf16 x (2 layouts) -> L2-norm -> MFMA logits -> softmax ->
// MFMA VLAD (persistent acc) -> PLAIN STORES to per-chunk vladp/asump.
// (256,2): round-3 showed (256,3)'s 170-VGPR cap spills softmax temps -> 2x slow.
// MFMA 16x16x32 bf16 layouts (HW-verified per guide):
//   A[m=lane&15][k=quad*8+j], B[k=quad*8+j][n=lane&15], D col=lane&15 row=4*quad+reg.
__global__ __launch_bounds__(BLK, 2) void netvlad_main(
    const float* __restrict__ x,
    const float* __restrict__ conv_w,
    const float* __restrict__ conv_b,
    float* __restrict__ vladp,   // [NCHUNK][Nn][Kk][Cc]  16 MB
    float* __restrict__ asump,   // [NCHUNK][Nn][Kk]      128 KB
    float* __restrict__ out)     // zeroed by block (0,0) for finalize atomics
{
    __shared__ __align__(16) unsigned short xC[Cc * XCS];  // 18432 B raw-x bf16 [c][s]
    __shared__ __align__(16) float Lbuf[ST * LKS];         // 17408 B logits [s][k] / xT alias
    __shared__ __align__(16) unsigned short aB[Kk * AS];   // 9216 B  a' bf16 [k][s]
    __shared__ float red[ST * RS];                         // 4352 B  ssq partials
    __shared__ float invn[ST];
    unsigned short* xT = (unsigned short*)Lbuf;            // raw-x bf16 [s][c]

    const int t     = threadIdx.x;
    const int n     = blockIdx.y;
    const int chunk = blockIdx.x;
    const int w    = t >> 6;      // wave id: k-rows 16w..16w+15
    const int l    = t & 63;
    const int m    = l & 15;
    const int quad = l >> 4;
    const int p    = t >> 2;      // softmax pixel
    const int ii   = t & 3;       // softmax k-slice

    // ---- out is poisoned each call: block (0,0) zeroes it (4096 floats).
    //      finalize launches after main completes (stream order) -> visible.
    if (chunk == 0 && n == 0) {
        float4 z4 = make_float4(0.f, 0.f, 0.f, 0.f);
#pragma unroll
        for (int i = 0; i < 4; ++i)
            ((float4*)out)[t + 256 * i] = z4;
    }

    // ---- one-time: conv_w A-fragments (bf16, regs) + bias for D rows ----
    short8 wfrag[4];
    {
        const float* wr_ = conv_w + (16 * w + m) * Cc;
#pragma unroll
        for (int ks = 0; ks < 4; ++ks) {
            float4 wa = *(const float4*)(wr_ + 32 * ks + 8 * quad);
            float4 wb = *(const float4*)(wr_ + 32 * ks + 8 * quad + 4);
            union { short8 s8; unsigned u[4]; } W_;
            W_.u[0] = pack2(wa.x, wa.y);
            W_.u[1] = pack2(wa.z, wa.w);
            W_.u[2] = pack2(wb.x, wb.y);
            W_.u[3] = pack2(wb.z, wb.w);
            wfrag[ks] = W_.s8;
        }
    }
    float bias_r[4];
#pragma unroll
    for (int r = 0; r < 4; ++r) bias_r[r] = conv_b[16 * w + 4 * quad + r];

    float4v acc[8];               // VLAD acc: 16k x 128c per wave, persistent
#pragma unroll
    for (int nt = 0; nt < 8; ++nt) acc[nt] = (float4v){0.f, 0.f, 0.f, 0.f};
    float asum_part[16];
#pragma unroll
    for (int j = 0; j < 16; ++j) asum_part[j] = 0.f;

    const float* xn = x + (size_t)n * Cc * Ss;

    // ---- register prefetch of subtile 0 ----
    const int sq   = (t & 15) << 2;
    const int crow = t >> 4;
    const float* xbase = xn + (size_t)crow * Ss + chunk * SCHUNK + sq;
    float4 pf[8];
#pragma unroll
    for (int r = 0; r < 8; ++r)
        pf[r] = *(const float4*)(xbase + (size_t)(16 * r) * Ss);

    for (int sub = 0; sub < NSUB; ++sub) {
        bar_lds();  // prior GEMM2 reads of xC/aB done

        // ---- stage: consume prefetched fp32 -> ssq partials + bf16 xC [c][s] ----
        {
            float sp0 = 0.f, sp1 = 0.f, sp2 = 0.f, sp3 = 0.f;
#pragma unroll
            for (int r = 0; r < 8; ++r) {
                float4 v = pf[r];
                sp0 += v.x * v.x; sp1 += v.y * v.y;
                sp2 += v.z * v.z; sp3 += v.w * v.w;
                uint2 pk = make_uint2(pack2(v.x, v.y), pack2(v.z, v.w));
                *(uint2*)&xC[(crow + 16 * r) * XCS + sq] = pk;
            }
            red[(sq + 0) * RS + crow] = sp0;
            red[(sq + 1) * RS + crow] = sp1;
            red[(sq + 2) * RS + crow] = sp2;
            red[(sq + 3) * RS + crow] = sp3;
        }
        // ---- issue next subtile's loads; they stay in flight across the raw
        //      barriers (no vmcnt drain) and land under GEMM1/softmax/GEMM2 ----
        if (sub < NSUB - 1) {
#pragma unroll
            for (int r = 0; r < 8; ++r)
                pf[r] = *(const float4*)(xbase + (size_t)(16 * r) * Ss + (sub + 1) * ST);
        }
        bar_lds();

        // ---- invn (t<64) ----
        if (t < ST) {
            float tot = 0.f;
#pragma unroll
            for (int i = 0; i < 16; ++i) tot += red[t * RS + i];
            invn[t] = 1.0f / fmaxf(sqrtf(tot), 1e-12f);
        }
        // ---- build xT [s][c] from xC (16B writes; lane-spread over s) ----
        {
            int s = t & 63, oct0 = t >> 6;
#pragma unroll
            for (int q = 0; q < 4; ++q) {
                int oct = oct0 + 4 * q;   // c-octet 0..15
                uint4 dd;
                dd.x = (unsigned)xC[(8 * oct + 0) * XCS + s] | ((unsigned)xC[(8 * oct + 1) * XCS + s] << 16);
                dd.y = (unsigned)xC[(8 * oct + 2) * XCS + s] | ((unsigned)xC[(8 * oct + 3) * XCS + s] << 16);
                dd.z = (unsigned)xC[(8 * oct + 4) * XCS + s] | ((unsigned)xC[(8 * oct + 5) * XCS + s] << 16);
                dd.w = (unsigned)xC[(8 * oct + 6) * XCS + s] | ((unsigned)xC[(8 * oct + 7) * XCS + s] << 16);
                *(uint4*)&xT[s * XTS + 8 * oct] = dd;
            }
        }
        bar_lds();

        // ---- GEMM1 (MFMA): L[16w+k][s] = W x rawX, wave does 4 s-tiles x 4 c-steps
        float4v Lr[4];
#pragma unroll
        for (int nt = 0; nt < 4; ++nt) Lr[nt] = (float4v){0.f, 0.f, 0.f, 0.f};
#pragma unroll
        for (int nt = 0; nt < 4; ++nt) {
#pragma unroll
            for (int ks = 0; ks < 4; ++ks) {
                short8 b = *(const short8*)&xT[(16 * nt + m) * XTS + 32 * ks + 8 * quad];
                Lr[nt] = __builtin_amdgcn_mfma_f32_16x16x32_bf16(wfrag[ks], b, Lr[nt], 0, 0, 0);
            }
        }
        bar_lds();  // all xT reads done -> safe to overwrite with Lbuf

        // epilogue: *invn[s] + bias[k]; write [s][k] fp32
#pragma unroll
        for (int nt = 0; nt < 4; ++nt) {
            float iv = invn[16 * nt + m];
            float4 o;
            o.x = Lr[nt].x * iv + bias_r[0];
            o.y = Lr[nt].y * iv + bias_r[1];
            o.z = Lr[nt].z * iv + bias_r[2];
            o.w = Lr[nt].w * iv + bias_r[3];
            *(float4*)&Lbuf[(16 * nt + m) * LKS + 16 * w + 4 * quad] = o;
        }
        bar_lds();

        // ---- softmax over k per pixel p (4-thread team via shfl) ----
        {
            float lv[16];
#pragma unroll
            for (int j = 0; j < 16; ++j) lv[j] = Lbuf[p * LKS + ii + 4 * j];
            float mx = lv[0];
#pragma unroll
            for (int j = 1; j < 16; ++j) mx = fmaxf(mx, lv[j]);
            mx = fmaxf(mx, __shfl_xor(mx, 1));
            mx = fmaxf(mx, __shfl_xor(mx, 2));
            float e[16];
            float lsum = 0.f;
#pragma unroll
            for (int j = 0; j < 16; ++j) { e[j] = __expf(lv[j] - mx); lsum += e[j]; }
            lsum += __shfl_xor(lsum, 1);
            lsum += __shfl_xor(lsum, 2);
            float itot = 1.0f / lsum;
            float sca  = itot * invn[p];   // fold invn into a' (x in GEMM2 is raw)
#pragma unroll
            for (int j = 0; j < 16; ++j) {
                float av = e[j] * itot;
                asum_part[j] += av;                               // raw a for centroid term
                aB[(ii + 4 * j) * AS + p] = (unsigned short)f2bf(e[j] * sca);
            }
        }
        bar_lds();

        // ---- GEMM2 (MFMA): V[16w+k][c] += a'[k][s] x rawX^T[s][c] ----
#pragma unroll
        for (int ks = 0; ks < 2; ++ks) {
            short8 af = *(const short8*)&aB[(16 * w + m) * AS + 32 * ks + 8 * quad];
#pragma unroll
            for (int nt = 0; nt < 8; ++nt) {
                short8 bf_ = *(const short8*)&xC[(16 * nt + m) * XCS + 32 * ks + 8 * quad];
                acc[nt] = __builtin_amdgcn_mfma_f32_16x16x32_bf16(af, bf_, acc[nt], 0, 0, 0);
            }
        }
    }

    // ---- commit vlad partials as PLAIN STORES (no atomics, no ws memset):
    //      lane holds D[k=16w+4quad+r][c=16nt+m]
    {
        float* vb = vladp + ((((size_t)chunk * Nn + n) * Kk) + 16 * w + 4 * quad) * Cc + m;
#pragma unroll
        for (int nt = 0; nt < 8; ++nt) {
            vb[0 * Cc + 16 * nt] = acc[nt].x;
            vb[1 * Cc + 16 * nt] = acc[nt].y;
            vb[2 * Cc + 16 * nt] = acc[nt].z;
            vb[3 * Cc + 16 * nt] = acc[nt].w;
        }
    }

    // ---- block-reduce asum then plain store per k (reuse Lbuf) ----
    __syncthreads();
#pragma unroll
    for (int j = 0; j < 16; ++j) Lbuf[p * LKS + ii + 4 * j] = asum_part[j];
    __syncthreads();
    if (t < Kk) {
        float s_ = 0.f;
        for (int p2 = 0; p2 < ST; ++p2) s_ += Lbuf[p2 * LKS + t];
        asump[((size_t)chunk * Nn + n) * Kk + t] = s_;
    }
}

// Finalize, 256 blocks = (n2, kgroup of 8 k's): chunk-reduce vladp -> intra-norm
// scale -> lastfc partial -> 4 atomicAdds/thread into zeroed out.
__global__ __launch_bounds__(BLK) void netvlad_final(
    const float* __restrict__ vladp,
    const float* __restrict__ asump,
    const float* __restrict__ centroids,
    const float* __restrict__ fc_w,
    float* __restrict__ out)
{
    __shared__ float asum_s[8];
    __shared__ float scale_s[8];
    __shared__ float4 osum[8 * 32];

    const int t   = threadIdx.x;
    const int bid = blockIdx.x;
    const int n2  = bid >> 3;
    const int kg  = bid & 7;
    const int kl  = t >> 5;       // k within group 0..7
    const int c4  = t & 31;       // float4 column index
    const int k2  = 8 * kg + kl;

    // chunk-reduce vladp -> v (each thread owns 4 c's of one k)
    float4 v = make_float4(0.f, 0.f, 0.f, 0.f);
    const float* vp = vladp + ((size_t)n2 * Kk + k2) * Cc + 4 * c4;
#pragma unroll
    for (int ch = 0; ch < NCHUNK; ++ch) {
        float4 u = *(const float4*)(vp + (size_t)ch * Nn * Kk * Cc);
        v.x += u.x; v.y += u.y; v.z += u.z; v.w += u.w;
    }
    // chunk-reduce asum (8 threads)
    if (t < 8) {
        float a = 0.f;
#pragma unroll
        for (int ch = 0; ch < NCHUNK; ++ch)
            a += asump[((size_t)ch * Nn + n2) * Kk + 8 * kg + t];
        asum_s[t] = a;
    }
    __syncthreads();

    const float a2 = asum_s[kl];
    float4 cv = *(const float4*)(centroids + (size_t)k2 * Cc + 4 * c4);
    float dx = v.x - a2 * cv.x;
    float dy = v.y - a2 * cv.y;
    float dz = v.z - a2 * cv.z;
    float dw = v.w - a2 * cv.w;

    float ssq = dx * dx + dy * dy + dz * dz + dw * dw;
    ssq += __shfl_xor(ssq, 1);
    ssq += __shfl_xor(ssq, 2);
    ssq += __shfl_xor(ssq, 4);
    ssq += __shfl_xor(ssq, 8);
    ssq += __shfl_xor(ssq, 16);
    if ((t & 31) == 0)
        scale_s[kl] = fc_w[k2] / fmaxf(sqrtf(ssq), 1e-12f);
    __syncthreads();

    const float sc = scale_s[kl];
    osum[kl * 32 + c4] = make_float4(sc * dx, sc * dy, sc * dz, sc * dw);
    __syncthreads();

    if (t < 32) {
        float4 tot = osum[t];
#pragma unroll
        for (int kl2 = 1; kl2 < 8; ++kl2) {
            float4 o2 = osum[kl2 * 32 + t];
            tot.x += o2.x; tot.y += o2.y; tot.z += o2.z; tot.w += o2.w;
        }
        atomicAdd(&out[n2 * Cc + 4 * t + 0], tot.x);
        atomicAdd(&out[n2 * Cc + 4 * t + 1], tot.y);
        atomicAdd(&out[n2 * Cc + 4 * t + 2], tot.z);
        atomicAdd(&out[n2 * Cc + 4 * t + 3], tot.w);
    }
}

extern "C" void kernel_launch(void* const* d_in, const int* in_sizes, int n_in,
                              void* d_out, int out_size, void* d_ws, size_t ws_size,
                              hipStream_t stream) {
    (void)in_sizes; (void)n_in; (void)out_size; (void)ws_size;
    const float* x         = (const float*)d_in[0];
    const float* conv_w    = (const float*)d_in[1];
    const float* conv_b    = (const float*)d_in[2];
    const float* centroids = (const float*)d_in[3];
    const float* fc_w      = (const float*)d_in[4];
    float* out = (float*)d_out;

    float* vladp = (float*)d_ws;                                   // [16][32][64][128] = 16 MB
    float* asump = vladp + (size_t)NCHUNK * Nn * Kk * Cc;          // [16][32][64] = 128 KB

    dim3 grid(NCHUNK, Nn);
    netvlad_main<<<grid, BLK, 0, stream>>>(x, conv_w, conv_b, vladp, asump, out);
    netvlad_final<<<dim3(Nn * 8), BLK, 0, stream>>>(vladp, asump, centroids, fc_w, out);
}